// Round 1
// baseline (231.007 us; speedup 1.0000x reference)
//
#include <hip/hip_runtime.h>

typedef short bf16x8 __attribute__((ext_vector_type(8)));     // 8 bf16 in 4 VGPRs
typedef float f32x4 __attribute__((ext_vector_type(4)));
typedef float float4v __attribute__((ext_vector_type(4)));
typedef unsigned short u16x8 __attribute__((ext_vector_type(8)));
typedef unsigned short u16x4 __attribute__((ext_vector_type(4)));

#define GLL16(g, l_) __builtin_amdgcn_global_load_lds( \
    (const __attribute__((address_space(1))) unsigned int*)(g), \
    (__attribute__((address_space(3))) unsigned int*)(l_), 16, 0, 0)

__device__ __forceinline__ unsigned short f2bf(float x) {
  unsigned u = __float_as_uint(x);
  u += 0x7fff + ((u >> 16) & 1);   // RNE
  return (unsigned short)(u >> 16);
}

// ---------------------------------------------------------------- cast
// X: 4M elems (2048 blocks), Wq/Wk/Wv/Wo: 1M each (512 blocks each)
__global__ __launch_bounds__(256) void cast_all_kernel(
    const float* __restrict__ X, const float* __restrict__ Wq,
    const float* __restrict__ Wk, const float* __restrict__ Wv,
    const float* __restrict__ Wo,
    unsigned short* __restrict__ Xb, unsigned short* __restrict__ Wb) {
  int bx = blockIdx.x;
  const float* src; unsigned short* dst; int rel;
  if (bx < 2048) { src = X; dst = Xb; rel = bx; }
  else {
    int wi = (bx - 2048) >> 9; rel = (bx - 2048) & 511;
    src = (wi == 0) ? Wq : (wi == 1) ? Wk : (wi == 2) ? Wv : Wo;
    dst = Wb + ((size_t)wi << 20);
  }
  size_t o = (size_t)rel * 2048 + (size_t)threadIdx.x * 8;
  const float4v* s4 = (const float4v*)(src + o);
  float4v v0 = s4[0], v1 = s4[1];
  u16x8 r;
  r[0]=f2bf(v0[0]); r[1]=f2bf(v0[1]); r[2]=f2bf(v0[2]); r[3]=f2bf(v0[3]);
  r[4]=f2bf(v1[0]); r[5]=f2bf(v1[1]); r[6]=f2bf(v1[2]); r[7]=f2bf(v1[3]);
  *(u16x8*)(dst + o) = r;
}

// ---------------------------------------------------------------- GEMM core
// C[128x128] = A[128xK] * Bt[128xK]^T, both row-major with row stride K.
// m97 structure: single-buffer LDS, global_load_lds width 16, 2 barriers/K-step.
__device__ __forceinline__ void gemm_core_128(
    const unsigned short* __restrict__ A, const unsigned short* __restrict__ Bt,
    int m0, int n0, int K,
    unsigned short* lA, unsigned short* lB, f32x4 acc[4][4]) {
  const int t = threadIdx.x;
  const int l = t & 63;
  const int wr = t >> 7, wc = (t >> 6) & 1;
  const int srow = t >> 3, scol = (t & 7) * 8;
  const int l15 = l & 15, lhi = l >> 4;
  for (int kt = 0; kt < K; kt += 64) {
#pragma unroll
    for (int p = 0; p < 4; ++p) {
      GLL16(A  + (size_t)(m0 + p * 32 + srow) * K + kt + scol, lA + (p * 32 + srow) * 64 + scol);
      GLL16(Bt + (size_t)(n0 + p * 32 + srow) * K + kt + scol, lB + (p * 32 + srow) * 64 + scol);
    }
    asm volatile("s_waitcnt vmcnt(0)" ::: "memory");
    __syncthreads();
#pragma unroll
    for (int ks = 0; ks < 2; ++ks) {
      bf16x8 af[4], bfr[4];
#pragma unroll
      for (int i = 0; i < 4; ++i) {
        af[i]  = *(const bf16x8*)(lA + (wr * 64 + i * 16 + l15) * 64 + ks * 32 + lhi * 8);
        bfr[i] = *(const bf16x8*)(lB + (wc * 64 + i * 16 + l15) * 64 + ks * 32 + lhi * 8);
      }
#pragma unroll
      for (int i = 0; i < 4; ++i)
#pragma unroll
        for (int j = 0; j < 4; ++j)
          acc[i][j] = __builtin_amdgcn_mfma_f32_16x16x32_bf16(af[i], bfr[j], acc[i][j], 0, 0, 0);
    }
    __syncthreads();
  }
}

// ---------------------------------------------------------------- QKV projection
// grid = 3 kinds * 32 mb * 8 nb = 768 blocks. V is written transposed per head.
__global__ __launch_bounds__(256) void qkv_gemm_kernel(
    const unsigned short* __restrict__ Xb, const unsigned short* __restrict__ Wb,
    const float* __restrict__ bq, const float* __restrict__ bk, const float* __restrict__ bv,
    unsigned short* __restrict__ Q, unsigned short* __restrict__ Kd,
    unsigned short* __restrict__ Vt, float qscale) {
  __shared__ __align__(16) unsigned short lA[128 * 64];
  __shared__ __align__(16) unsigned short lB[128 * 64];
  const int bx = blockIdx.x;
  const int kind = bx >> 8;          // 0=Q 1=K 2=V
  const int r = bx & 255;
  const int mb = r >> 3, nb = r & 7;
  const unsigned short* Bt = Wb + ((size_t)kind << 20);
  const float* bias = (kind == 0) ? bq : (kind == 1) ? bk : bv;
  f32x4 acc[4][4];
#pragma unroll
  for (int i = 0; i < 4; ++i)
#pragma unroll
    for (int j = 0; j < 4; ++j)
#pragma unroll
      for (int r0 = 0; r0 < 4; ++r0) acc[i][j][r0] = 0.f;
  gemm_core_128(Xb, Bt, mb * 128, nb * 128, 1024, lA, lB, acc);
  const int t = threadIdx.x, l = t & 63;
  const int wr = t >> 7, wc = (t >> 6) & 1;
  const int l15 = l & 15, lhi = l >> 4;
  if (kind == 2) {
    // Vt[b][h][d][s] so attention PV B-frags are contiguous in s
#pragma unroll
    for (int i = 0; i < 4; ++i)
#pragma unroll
      for (int j = 0; j < 4; ++j) {
        int gn = nb * 128 + wc * 64 + j * 16 + l15;
        float bb_ = bias[gn];
        int gm0 = mb * 128 + wr * 64 + i * 16 + lhi * 4;
        int h = gn >> 6, d = gn & 63;
        int batch = gm0 >> 11, s = gm0 & 2047;
        u16x4 pk;
#pragma unroll
        for (int r0 = 0; r0 < 4; ++r0) pk[r0] = f2bf(acc[i][j][r0] + bb_);
        *(u16x4*)(Vt + ((size_t)(batch * 16 + h) * 64 + d) * 2048 + s) = pk;
      }
  } else {
    unsigned short* Out = (kind == 0) ? Q : Kd;
    float sc_ = (kind == 0) ? qscale : 1.0f;   // log2(e)/8 folded into Q
#pragma unroll
    for (int i = 0; i < 4; ++i)
#pragma unroll
      for (int j = 0; j < 4; ++j) {
        int gn = nb * 128 + wc * 64 + j * 16 + l15;
        float bb_ = bias[gn];
        int gm0 = mb * 128 + wr * 64 + i * 16 + lhi * 4;
#pragma unroll
        for (int r0 = 0; r0 < 4; ++r0)
          Out[(size_t)(gm0 + r0) * 1024 + gn] = f2bf((acc[i][j][r0] + bb_) * sc_);
      }
  }
}

// ---------------------------------------------------------------- flash attention
// grid = 32 (b,h) * 16 qblocks = 512 blocks; 4 independent waves * 32 q-rows.
// K and Vt b-frags read straight from global (L2-resident); only P goes via LDS
// with XOR swizzle (row-major [32][128B] would be a 16-way bank conflict).
__global__ __launch_bounds__(256) void attn_kernel(
    const unsigned short* __restrict__ Q, const unsigned short* __restrict__ Kd,
    const unsigned short* __restrict__ Vt, unsigned short* __restrict__ Ao) {
  __shared__ __align__(16) unsigned short pl[4][32 * 64];
  const int bx = blockIdx.x;
  const int bh = bx >> 4, qb = bx & 15;
  const int b = bh >> 4, h = bh & 15;
  const int t = threadIdx.x, l = t & 63, w = t >> 6;
  const int l15 = l & 15, lhi = l >> 4;
  const int q0 = b * 2048 + qb * 128 + w * 32;
  const unsigned short* Qp = Q + (size_t)q0 * 1024 + h * 64;
  const unsigned short* Kp = Kd + (size_t)b * 2048 * 1024 + h * 64;
  const unsigned short* Vp = Vt + (size_t)bh * 64 * 2048;
  char* plw = (char*)pl[w];

  bf16x8 qa[2][2];   // Q a-frags, hoisted for the whole kernel
#pragma unroll
  for (int rf = 0; rf < 2; ++rf)
#pragma unroll
    for (int ks = 0; ks < 2; ++ks)
      qa[rf][ks] = *(const bf16x8*)(Qp + (size_t)(rf * 16 + l15) * 1024 + ks * 32 + lhi * 8);

  f32x4 acc[2][4];
  float mrow[2][4], lrow[2][4];
#pragma unroll
  for (int rf = 0; rf < 2; ++rf)
#pragma unroll
    for (int j = 0; j < 4; ++j) {
      mrow[rf][j] = -__builtin_inff();
      lrow[rf][j] = 0.f;
#pragma unroll
      for (int r0 = 0; r0 < 4; ++r0) acc[rf][j][r0] = 0.f;
    }

  for (int kb = 0; kb < 2048; kb += 64) {
    // ---- scores = Q * K^T (already scaled by log2e/8 via Q)
    f32x4 sc[2][4];
#pragma unroll
    for (int rf = 0; rf < 2; ++rf)
#pragma unroll
      for (int cf = 0; cf < 4; ++cf)
#pragma unroll
        for (int r0 = 0; r0 < 4; ++r0) sc[rf][cf][r0] = 0.f;
#pragma unroll
    for (int ks = 0; ks < 2; ++ks) {
      bf16x8 kf[4];
#pragma unroll
      for (int cf = 0; cf < 4; ++cf)
        kf[cf] = *(const bf16x8*)(Kp + (size_t)(kb + cf * 16 + l15) * 1024 + ks * 32 + lhi * 8);
#pragma unroll
      for (int rf = 0; rf < 2; ++rf)
#pragma unroll
        for (int cf = 0; cf < 4; ++cf)
          sc[rf][cf] = __builtin_amdgcn_mfma_f32_16x16x32_bf16(qa[rf][ks], kf[cf], sc[rf][cf], 0, 0, 0);
    }
    // ---- online softmax (base 2); rows live at (lhi*4 + r0), cols at (cf*16 + l15)
#pragma unroll
    for (int rf = 0; rf < 2; ++rf) {
#pragma unroll
      for (int r0 = 0; r0 < 4; ++r0) {
        float mx = fmaxf(fmaxf(sc[rf][0][r0], sc[rf][1][r0]),
                         fmaxf(sc[rf][2][r0], sc[rf][3][r0]));
#pragma unroll
        for (int d = 1; d < 16; d <<= 1) mx = fmaxf(mx, __shfl_xor(mx, d));
        float mnew = fmaxf(mrow[rf][r0], mx);
        float c = exp2f(mrow[rf][r0] - mnew);
        mrow[rf][r0] = mnew;
        float rs = 0.f;
#pragma unroll
        for (int cf = 0; cf < 4; ++cf) {
          float p = exp2f(sc[rf][cf][r0] - mnew);
          sc[rf][cf][r0] = p;
          rs += p;
        }
#pragma unroll
        for (int d = 1; d < 16; d <<= 1) rs += __shfl_xor(rs, d);
        lrow[rf][r0] = lrow[rf][r0] * c + rs;
#pragma unroll
        for (int df = 0; df < 4; ++df) acc[rf][df][r0] *= c;
      }
      // ---- P -> LDS (bf16), XOR-swizzled
#pragma unroll
      for (int cf = 0; cf < 4; ++cf)
#pragma unroll
        for (int r0 = 0; r0 < 4; ++r0) {
          int row = rf * 16 + lhi * 4 + r0;
          int off = row * 128 + ((((cf * 16 + l15) * 2)) ^ ((row & 7) << 4));
          *(unsigned short*)(plw + off) = f2bf(sc[rf][cf][r0]);
        }
    }
    // ---- out += P * V
#pragma unroll
    for (int ks = 0; ks < 2; ++ks) {
      bf16x8 pa[2], vf[4];
#pragma unroll
      for (int rf = 0; rf < 2; ++rf) {
        int row = rf * 16 + l15;
        pa[rf] = *(const bf16x8*)(plw + row * 128 + (((ks * 32 + lhi * 8) * 2) ^ ((row & 7) << 4)));
      }
#pragma unroll
      for (int df = 0; df < 4; ++df)
        vf[df] = *(const bf16x8*)(Vp + (size_t)(df * 16 + l15) * 2048 + kb + ks * 32 + lhi * 8);
#pragma unroll
      for (int rf = 0; rf < 2; ++rf)
#pragma unroll
        for (int df = 0; df < 4; ++df)
          acc[rf][df] = __builtin_amdgcn_mfma_f32_16x16x32_bf16(pa[rf], vf[df], acc[rf][df], 0, 0, 0);
    }
  }
  // ---- epilogue: normalize and store merged-head layout [token][1024]
#pragma unroll
  for (int rf = 0; rf < 2; ++rf)
#pragma unroll
    for (int df = 0; df < 4; ++df)
#pragma unroll
      for (int r0 = 0; r0 < 4; ++r0) {
        int grow = q0 + rf * 16 + lhi * 4 + r0;
        int gcol = h * 64 + df * 16 + l15;
        Ao[(size_t)grow * 1024 + gcol] = f2bf(acc[rf][df][r0] / lrow[rf][r0]);
      }
}

// ---------------------------------------------------------------- output projection
__global__ __launch_bounds__(256) void out_gemm_kernel(
    const unsigned short* __restrict__ Ab, const unsigned short* __restrict__ Wob,
    const float* __restrict__ bo, float* __restrict__ Out) {
  __shared__ __align__(16) unsigned short lA[128 * 64];
  __shared__ __align__(16) unsigned short lB[128 * 64];
  const int bx = blockIdx.x;
  const int mb = bx >> 3, nb = bx & 7;
  f32x4 acc[4][4];
#pragma unroll
  for (int i = 0; i < 4; ++i)
#pragma unroll
    for (int j = 0; j < 4; ++j)
#pragma unroll
      for (int r0 = 0; r0 < 4; ++r0) acc[i][j][r0] = 0.f;
  gemm_core_128(Ab, Wob, mb * 128, nb * 128, 1024, lA, lB, acc);
  const int t = threadIdx.x, l = t & 63;
  const int wr = t >> 7, wc = (t >> 6) & 1;
  const int l15 = l & 15, lhi = l >> 4;
#pragma unroll
  for (int i = 0; i < 4; ++i)
#pragma unroll
    for (int j = 0; j < 4; ++j) {
      int gn = nb * 128 + wc * 64 + j * 16 + l15;
      float bb_ = bo[gn];
      int gm0 = mb * 128 + wr * 64 + i * 16 + lhi * 4;
#pragma unroll
      for (int r0 = 0; r0 < 4; ++r0)
        Out[(size_t)(gm0 + r0) * 1024 + gn] = acc[i][j][r0] + bb_;
    }
}

// ---------------------------------------------------------------- launcher
extern "C" void kernel_launch(void* const* d_in, const int* in_sizes, int n_in,
                              void* d_out, int out_size, void* d_ws, size_t ws_size,
                              hipStream_t stream) {
  const float* X  = (const float*)d_in[0];
  const float* Wq = (const float*)d_in[1];
  const float* bq = (const float*)d_in[2];
  const float* Wk = (const float*)d_in[3];
  const float* bk = (const float*)d_in[4];
  const float* Wv = (const float*)d_in[5];
  const float* bv = (const float*)d_in[6];
  const float* Wo = (const float*)d_in[7];
  const float* bo = (const float*)d_in[8];
  char* ws = (char*)d_ws;
  // ws layout (48 MB total)
  unsigned short* Xb = (unsigned short*)(ws);                     //  8 MB
  unsigned short* Wb = (unsigned short*)(ws + ((size_t)8  << 20)); //  8 MB (Wq,Wk,Wv,Wo bf16)
  unsigned short* Qb = (unsigned short*)(ws + ((size_t)16 << 20)); //  8 MB
  unsigned short* Kb = (unsigned short*)(ws + ((size_t)24 << 20)); //  8 MB
  unsigned short* Vt = (unsigned short*)(ws + ((size_t)32 << 20)); //  8 MB (transposed per head)
  unsigned short* Ab = (unsigned short*)(ws + ((size_t)40 << 20)); //  8 MB

  const float qscale = 1.4426950408889634f / 8.0f;  // log2(e)/sqrt(hd)

  cast_all_kernel<<<4096, 256, 0, stream>>>(X, Wq, Wk, Wv, Wo, Xb, Wb);
  qkv_gemm_kernel<<<768, 256, 0, stream>>>(Xb, Wb, bq, bk, bv, Qb, Kb, Vt, qscale);
  attn_kernel<<<512, 256, 0, stream>>>(Qb, Kb, Vt, Ab);
  out_gemm_kernel<<<256, 256, 0, stream>>>(Ab, Wb + ((size_t)3 << 20), bo, (float*)d_out);
}